// Round 15
// baseline (343.365 us; speedup 1.0000x reference)
//
#include <hip/hip_runtime.h>

#define EMB_DIM 256
#define HW 4096
#define N_EMB 1024
#define TOT_ELEMS (32 * HW * EMB_DIM)   // 33554432

typedef __attribute__((ext_vector_type(4)))  float f32x4;
typedef __attribute__((ext_vector_type(16))) float f32x16;
typedef __attribute__((ext_vector_type(4)))  int   i32x4;
typedef __attribute__((ext_vector_type(8)))  int   i32x8;

// ws layout (bytes)
#define WS_EMBQ_OFF 0             // 256 KB fp8(e4m3) swizzled emb (R13 layout)
#define WS_E2_OFF   262144        // 1024 f32 ||e||^2
#define WS_PSC_OFF  266240        // 256 f32 block partials

#define GRID_MAIN 256             // 1 block/CU, 8 waves, 512 rows/block
#define ESCALE 65536.0f
#define INV2SCALE 3.0517578125e-5f
#define SCL_ONE 127               // e8m0 neutral scale (2^0)

// ---------------------------------------------------------------------------
// Kernel 0: emb fp32 -> fp8 e4m3 (x65536), swizzled chunk layout + e2=||e||^2.
// chunk = e>>6, row el = e&63 (256B), byte cb ^ ((el&15)<<4).
// (verified R13/R14: correct MX numerics)
// ---------------------------------------------------------------------------
__global__ __launch_bounds__(64) void prep_emb(const float* __restrict__ emb,
                                               char* __restrict__ embq,
                                               float* __restrict__ e2) {
    const int e = blockIdx.x, ln = threadIdx.x;
    const float4 v = reinterpret_cast<const float4*>(emb)[e * 64 + ln];
    float s = v.x * v.x + v.y * v.y + v.z * v.z + v.w * v.w;

    unsigned d = 0;
    d = (unsigned)__builtin_amdgcn_cvt_pk_fp8_f32(v.x * ESCALE, v.y * ESCALE, (int)d, false);
    d = (unsigned)__builtin_amdgcn_cvt_pk_fp8_f32(v.z * ESCALE, v.w * ESCALE, (int)d, true);

    const int el = e & 63, ch = e >> 6;
    const int cb = (ln * 4) ^ ((el & 15) << 4);
    *reinterpret_cast<unsigned*>(embq + ch * 16384 + el * 256 + cb) = d;

#pragma unroll
    for (int o = 32; o; o >>= 1) s += __shfl_down(s, o);
    if (ln == 0) e2[e] = s;
}

// ---------------------------------------------------------------------------
// Kernel 1: emb-resident fused copy + sum(x^2) + MX-fp8 GEMM + min.
// INVERTED RESIDENCY (R9-R14 post-mortems: persistent x-fragments always
// spill): each wave pins its 128 e's x 256 k fp8 = 128 AGPRs ONCE (A-frags,
// from L2-resident embq); x streams through a 2x32KB fp8 LDS slab shared by
// all 8 waves. Per-wave arch demand ~118 < 128 by construction. No role
// split; 1 barrier/slice (4 slices of 128 rows). Staging: scalar-coalesced
// x loads -> out stores + x^2 + cvt_pk -> swizzled ds_write. Cross-wave
// min via minw[2][8][128] dbuf folded next slice.
// MFMA mfma_scale_f32_32x32x64_f8f6f4 (R13-verified layouts):
// A lane: e-row=lane&31, 32 k-bytes at half lane>>5; B same with x-row;
// D[e][m]: m=lane&31, e=(reg&3)+8*(reg>>2)+4*(lane>>5).
// score = e2 - 2^-15 * (A.B)
// ---------------------------------------------------------------------------
__global__ __launch_bounds__(512)
void vq_main(const float* __restrict__ x,
             float* __restrict__ out,
             const char* __restrict__ embq,
             const float* __restrict__ e2,
             float* __restrict__ psc) {
    __shared__ char  slab[2][32768];       // fp8 x slice: 128 rows x 256B (swz)
    __shared__ float minw[2][8][128];      // per-wave row-mins, dbuf
    __shared__ float e2l[1024];
    __shared__ float redbuf[8];
    const int tid = threadIdx.x;
    const int wv = tid >> 6, ln = tid & 63;
    const int m = ln & 31, h = ln >> 5;    // MFMA lane coords
    const int row = tid & 127, kq = tid >> 7;  // staging coords
    const int swr = (row & 15) << 4;
    const int swm = (m & 15) << 4;

    const int row_blk = blockIdx.x << 9;   // 512 rows/block
    const int b = row_blk >> 12, n_base = row_blk & 4095;
    const unsigned xbase = (unsigned)(b * (EMB_DIM * HW) + n_base);

    // ---- bootstrap: e2 -> LDS ----
    e2l[tid] = e2[tid];
    e2l[tid + 512] = e2[tid + 512];

    // ---- bootstrap: pin wave's 128 e's as A-fragments (128 AGPRs) ----
    // tiles: e in [64w,64w+32), [64w+32,64w+64), [512+64w,..), [512+64w+32,..)
    i32x8 ea[4][4];
#pragma unroll
    for (int t = 0; t < 4; ++t) {
        const int ebt = (t & 2) * 256 + 64 * wv + (t & 1) * 32;
        const int el = (ebt & 63) + m;
        const char* gp = embq + (ebt >> 6) * 16384 + el * 256;
#pragma unroll
        for (int kw = 0; kw < 4; ++kw) {
            const int bo = kw * 64 + h * 32;
            const i32x4 lo = *reinterpret_cast<const i32x4*>(gp + ((bo)      ^ swm));
            const i32x4 hi = *reinterpret_cast<const i32x4*>(gp + ((bo + 16) ^ swm));
            i32x8 f;
#pragma unroll
            for (int d = 0; d < 4; ++d) { f[d] = lo[d]; f[d + 4] = hi[d]; }
            ea[t][kw] = f;
            asm volatile("" : "+a"(ea[t][kw]));   // pin to AGPR (R4..R13 fix)
        }
    }

    float x2s = 0.f, sumb = 0.f;

    // stage 4 j-rounds (16 k-quads each thread total covers its row's 64B/4)
#define BURST(SL, Q) do {                                                     \
        _Pragma("unroll")                                                     \
        for (int j_ = 4 * (Q); j_ < 4 * (Q) + 4; ++j_) {                      \
            const int k0_ = 16 * j_ + 4 * kq;                                 \
            const unsigned gb_ = xbase + (unsigned)(k0_ * HW)                 \
                               + (unsigned)((SL) * 128 + row);                \
            const float f0_ = x[gb_],          f1_ = x[gb_ + HW];             \
            const float f2_ = x[gb_ + 2 * HW], f3_ = x[gb_ + 3 * HW];         \
            out[gb_] = f0_;          out[gb_ + HW] = f1_;                     \
            out[gb_ + 2 * HW] = f2_; out[gb_ + 3 * HW] = f3_;                 \
            x2s += f0_ * f0_ + f1_ * f1_ + f2_ * f2_ + f3_ * f3_;             \
            unsigned t_ = 0;                                                  \
            t_ = (unsigned)__builtin_amdgcn_cvt_pk_fp8_f32(f0_, f1_, (int)t_, false); \
            t_ = (unsigned)__builtin_amdgcn_cvt_pk_fp8_f32(f2_, f3_, (int)t_, true);  \
            *reinterpret_cast<unsigned*>(&slab[(SL) & 1][row * 256 + (k0_ ^ swr)]) = t_; \
        }                                                                     \
        __builtin_amdgcn_sched_barrier(0);                                    \
    } while (0)

    // one row-tile: B-frags from slab, 16 MFMA (4 e-tiles x 4 kw), fold mins
#define RT(S, RTI) do {                                                       \
        const char* pr_ = &slab[(S) & 1][(RTI * 32 + m) * 256];               \
        i32x8 bf_[4];                                                         \
        _Pragma("unroll")                                                     \
        for (int kw_ = 0; kw_ < 4; ++kw_) {                                   \
            const int bo_ = kw_ * 64 + h * 32;                                \
            const i32x4 lo_ = *reinterpret_cast<const i32x4*>(pr_ + ((bo_)      ^ swm)); \
            const i32x4 hi_ = *reinterpret_cast<const i32x4*>(pr_ + ((bo_ + 16) ^ swm)); \
            i32x8 f_;                                                         \
            _Pragma("unroll")                                                 \
            for (int d_ = 0; d_ < 4; ++d_) { f_[d_] = lo_[d_]; f_[d_ + 4] = hi_[d_]; } \
            bf_[kw_] = f_;                                                    \
        }                                                                     \
        float bst_ = 3.0e38f;                                                 \
        _Pragma("unroll")                                                     \
        for (int ep_ = 0; ep_ < 2; ++ep_) {                                   \
            f32x16 a0_ = {0.f,0.f,0.f,0.f,0.f,0.f,0.f,0.f,0.f,0.f,0.f,0.f,0.f,0.f,0.f,0.f}; \
            f32x16 a1_ = a0_;                                                 \
            _Pragma("unroll")                                                 \
            for (int kw_ = 0; kw_ < 4; ++kw_) {                               \
                a0_ = __builtin_amdgcn_mfma_scale_f32_32x32x64_f8f6f4(        \
                          ea[2 * ep_][kw_],     bf_[kw_], a0_, 0, 0, 0, SCL_ONE, 0, SCL_ONE); \
                a1_ = __builtin_amdgcn_mfma_scale_f32_32x32x64_f8f6f4(        \
                          ea[2 * ep_ + 1][kw_], bf_[kw_], a1_, 0, 0, 0, SCL_ONE, 0, SCL_ONE); \
            }                                                                 \
            const float* z0_ = e2l + ep_ * 512 + 64 * wv + 4 * h;             \
            const float* z1_ = z0_ + 32;                                      \
            _Pragma("unroll")                                                 \
            for (int q_ = 0; q_ < 4; ++q_) {                                  \
                const f32x4 ev0_ = *reinterpret_cast<const f32x4*>(z0_ + 8 * q_); \
                const f32x4 ev1_ = *reinterpret_cast<const f32x4*>(z1_ + 8 * q_); \
                _Pragma("unroll")                                             \
                for (int r_ = 0; r_ < 4; ++r_) {                              \
                    bst_ = fminf(bst_, fmaf(-INV2SCALE, a0_[4 * q_ + r_], ev0_[r_])); \
                    bst_ = fminf(bst_, fmaf(-INV2SCALE, a1_[4 * q_ + r_], ev1_[r_])); \
                }                                                             \
            }                                                                 \
        }                                                                     \
        bst_ = fminf(bst_, __shfl_xor(bst_, 32));                             \
        if (h == 0) minw[(S) & 1][wv][RTI * 32 + m] = bst_;                   \
    } while (0)

    // fold previous slice's cross-wave mins (tid<128, one row each)
#define FOLD(S) do {                                                          \
        if (tid < 128) {                                                      \
            float v_ = minw[(S) & 1][0][tid];                                 \
            _Pragma("unroll")                                                 \
            for (int w_ = 1; w_ < 8; ++w_) v_ = fminf(v_, minw[(S) & 1][w_][tid]); \
            sumb += v_;                                                       \
        }                                                                     \
    } while (0)

#define SLICE(S) do {                                                         \
        _Pragma("unroll")                                                     \
        for (int q_ = 0; q_ < 4; ++q_) {                                      \
            if ((S) < 3) BURST((S) + 1, q_);                                  \
            RT(S, q_);                                                        \
        }                                                                     \
        if ((S) > 0) FOLD((S) - 1);                                           \
        __syncthreads();                                                      \
    } while (0)

    // ---- bootstrap: stage slice 0 ----
    BURST(0, 0); BURST(0, 1); BURST(0, 2); BURST(0, 3);
    __syncthreads();

    SLICE(0);
    SLICE(1);
    SLICE(2);
    SLICE(3);
    FOLD(3);   // slice 3's mins (minw[1]), after its barrier

    // ---- block reduction: x2s (all) + sumb (tid<128) ----
    float contrib = x2s + sumb;
#pragma unroll
    for (int o = 32; o; o >>= 1) contrib += __shfl_down(contrib, o);
    if (ln == 0) redbuf[wv] = contrib;
    __syncthreads();
    if (tid == 0) {
        float s = 0.f;
#pragma unroll
        for (int i = 0; i < 8; ++i) s += redbuf[i];
        psc[blockIdx.x] = s;
    }
#undef BURST
#undef RT
#undef FOLD
#undef SLICE
}

// ---------------------------------------------------------------------------
// Kernel 2: deterministic tree-reduce of partials -> loss scalar.
// ---------------------------------------------------------------------------
__global__ __launch_bounds__(256) void finalize(const float* __restrict__ psc,
                                                float* __restrict__ out_loss) {
    __shared__ float red[256];
    const int t = threadIdx.x;
    red[t] = psc[t];
    __syncthreads();
    for (int hh = 128; hh; hh >>= 1) {
        if (t < hh) red[t] += red[t + hh];
        __syncthreads();
    }
    if (t == 0) *out_loss = 1.25f * red[0] / (float)TOT_ELEMS;
}

extern "C" void kernel_launch(void* const* d_in, const int* in_sizes, int n_in,
                              void* d_out, int out_size, void* d_ws, size_t ws_size,
                              hipStream_t stream) {
    const float* x = (const float*)d_in[0];
    const float* emb = (const float*)d_in[1];
    float* out = (float*)d_out;
    char* ws = (char*)d_ws;

    char*  embq = ws + WS_EMBQ_OFF;
    float* e2   = (float*)(ws + WS_E2_OFF);
    float* psc  = (float*)(ws + WS_PSC_OFF);

    prep_emb<<<N_EMB, 64, 0, stream>>>(emb, embq, e2);
    vq_main<<<GRID_MAIN, 512, 0, stream>>>(x, out, embq, e2, psc);
    finalize<<<1, 256, 0, stream>>>(psc, out + TOT_ELEMS);
}

// Round 16
// 119.248 us; speedup vs baseline: 2.8794x; 2.8794x over previous
//
#include <hip/hip_runtime.h>

#define EMB_DIM 256
#define HW 4096
#define N_EMB 1024
#define TOT_ELEMS (32 * HW * EMB_DIM)   // 33554432

typedef __attribute__((ext_vector_type(4)))  float f32x4;
typedef __attribute__((ext_vector_type(16))) float f32x16;
typedef __attribute__((ext_vector_type(4)))  int   i32x4;
typedef __attribute__((ext_vector_type(8)))  int   i32x8;

// ws layout (bytes)
#define WS_EMBQ_OFF 0             // 256 KB fp8(e4m3) swizzled emb (R13 layout)
#define WS_E2_OFF   262144        // 1024 f32 ||e||^2
#define WS_PSC_OFF  266240        // 1024 f32 dist-kernel partials
#define WS_PX2_OFF  270336        // 2048 f32 copy-kernel partials
#define WS_XQ_OFF   278528        // 32 MB fp8 x, B-fragment tile layout
#define WS_NEED     (278528u + 33554432u)

#define COPYQ_BLOCKS 2048         // 64 rows/block
#define DIST_BLOCKS  1024         // 128 rows/block, 4 waves x 32 rows
#define FUSED_BLOCKS 1024
#define ESCALE 65536.0f           // emb pre-scale: |e|<2^-10 -> |ê|<64
#define INV2SCALE 3.0517578125e-5f
#define SCL_ONE 127               // e8m0 neutral scale (2^0)

typedef const __attribute__((address_space(1))) unsigned int* gas_u32p;
typedef __attribute__((address_space(3))) unsigned int* las_u32p;
__device__ __forceinline__ void gll16(const void* g, void* l) {
    __builtin_amdgcn_global_load_lds((gas_u32p)g, (las_u32p)l, 16, 0, 0);
}

// ---------------------------------------------------------------------------
// Kernel 0: emb fp32 -> fp8 e4m3 (x65536), swizzled chunk layout + e2=||e||^2.
// chunk=e>>6, row el=e&63 (256B), byte cb ^ ((el&15)<<4).  (R13-verified)
// ---------------------------------------------------------------------------
__global__ __launch_bounds__(64) void prep_emb(const float* __restrict__ emb,
                                               char* __restrict__ embq,
                                               float* __restrict__ e2) {
    const int e = blockIdx.x, ln = threadIdx.x;
    const float4 v = reinterpret_cast<const float4*>(emb)[e * 64 + ln];
    float s = v.x * v.x + v.y * v.y + v.z * v.z + v.w * v.w;

    unsigned d = 0;
    d = (unsigned)__builtin_amdgcn_cvt_pk_fp8_f32(v.x * ESCALE, v.y * ESCALE, (int)d, false);
    d = (unsigned)__builtin_amdgcn_cvt_pk_fp8_f32(v.z * ESCALE, v.w * ESCALE, (int)d, true);

    const int el = e & 63, ch = e >> 6;
    const int cb = (ln * 4) ^ ((el & 15) << 4);
    *reinterpret_cast<unsigned*>(embq + ch * 16384 + el * 256 + cb) = d;

#pragma unroll
    for (int o = 32; o; o >>= 1) s += __shfl_down(s, o);
    if (ln == 0) e2[e] = s;
}

// ---------------------------------------------------------------------------
// Kernel A (split path): streaming copy + sum(x^2) + fp8-quantize x into the
// B-fragment tile layout: byte (row r, k) -> xq[((t*4+kf)*2+h)*1024 + m*32 +
// (k&31)] with t=r>>5, m=r&31, kf=k>>6, h=(k>>5)&1. Thread = (row nlane,
// k-group kg): 64 coalesced scalar loads/stores (256B/instr across 64 lanes),
// 4x16B coalesced xq stores. ~40 regs, no barriers in hot path.
// ---------------------------------------------------------------------------
__global__ __launch_bounds__(256)
void copy_quant(const float* __restrict__ x, float* __restrict__ out,
                char* __restrict__ xq, float* __restrict__ px2) {
    const int tid = threadIdx.x;
    const int nlane = tid & 63, kg = tid >> 6;
    const int rb = blockIdx.x << 6;
    const int b = rb >> 12, n0 = rb & 4095;
    const unsigned gb = (unsigned)(b * (EMB_DIM * HW) + n0 + nlane);
    const int r = rb + nlane;
    const int t = r >> 5, m = r & 31;

    float x2s = 0.f;
#pragma unroll
    for (int h = 0; h < 2; ++h) {
        unsigned dw[8];
#pragma unroll
        for (int sr = 0; sr < 2; ++sr) {
            float v[16];
#pragma unroll
            for (int j = 0; j < 16; ++j) {
                const int k = kg * 64 + h * 32 + sr * 16 + j;
                const unsigned o = gb + (unsigned)(k * HW);
                const float f = x[o];
                out[o] = f;
                x2s += f * f;
                v[j] = f;
            }
#pragma unroll
            for (int d = 0; d < 4; ++d) {
                unsigned tw = 0;
                tw = (unsigned)__builtin_amdgcn_cvt_pk_fp8_f32(v[4*d],   v[4*d+1], (int)tw, false);
                tw = (unsigned)__builtin_amdgcn_cvt_pk_fp8_f32(v[4*d+2], v[4*d+3], (int)tw, true);
                dw[sr * 4 + d] = tw;
            }
        }
        char* q = xq + (((t * 4 + kg) * 2 + h) << 10) + m * 32;
        *reinterpret_cast<i32x4*>(q) = i32x4{(int)dw[0], (int)dw[1], (int)dw[2], (int)dw[3]};
        *reinterpret_cast<i32x4*>(q + 16) = i32x4{(int)dw[4], (int)dw[5], (int)dw[6], (int)dw[7]};
    }

#pragma unroll
    for (int o = 32; o; o >>= 1) x2s += __shfl_down(x2s, o);
    __shared__ float wsum[4];
    if ((tid & 63) == 0) wsum[tid >> 6] = x2s;
    __syncthreads();
    if (tid == 0) px2[blockIdx.x] = (wsum[0] + wsum[1]) + (wsum[2] + wsum[3]);
}

// ---- shared e-loop body (R13-verified): MX MFMA vs LDS-staged emb chunk ----
#define STAGE_EMB_Q(CC, BUF) do {                                             \
        const char* gs_ = embq + (CC) * 16384 + wv * 4096 + ln * 16;          \
        char* lb_ = smem + (BUF) * 16384 + wv * 4096;                         \
        _Pragma("unroll")                                                     \
        for (int i_ = 0; i_ < 4; ++i_) gll16(gs_ + i_ * 1024, lb_ + i_ * 1024); \
    } while (0)

#define TLOOP_MX(BX, CC) do {                                                 \
        const char* bufb_ = smem + ((CC) & 1) * 16384;                        \
        const char* p0_ = bufb_ + m * 256;                                    \
        const char* p1_ = p0_ + 32 * 256;                                     \
        f32x16 a0_ = {0.f,0.f,0.f,0.f,0.f,0.f,0.f,0.f,0.f,0.f,0.f,0.f,0.f,0.f,0.f,0.f}; \
        f32x16 a1_ = a0_;                                                     \
        _Pragma("unroll")                                                     \
        for (int kf_ = 0; kf_ < 4; ++kf_) {                                   \
            const int bo_ = kf_ * 64 + h * 32;                                \
            const i32x4 lo0_ = *reinterpret_cast<const i32x4*>(p0_ + ((bo_)      ^ sw)); \
            const i32x4 hi0_ = *reinterpret_cast<const i32x4*>(p0_ + ((bo_ + 16) ^ sw)); \
            const i32x4 lo1_ = *reinterpret_cast<const i32x4*>(p1_ + ((bo_)      ^ sw)); \
            const i32x4 hi1_ = *reinterpret_cast<const i32x4*>(p1_ + ((bo_ + 16) ^ sw)); \
            i32x8 e0_, e1_;                                                   \
            _Pragma("unroll")                                                 \
            for (int d_ = 0; d_ < 4; ++d_) {                                  \
                e0_[d_] = lo0_[d_]; e0_[d_ + 4] = hi0_[d_];                   \
                e1_[d_] = lo1_[d_]; e1_[d_ + 4] = hi1_[d_];                   \
            }                                                                 \
            a0_ = __builtin_amdgcn_mfma_scale_f32_32x32x64_f8f6f4(            \
                      e0_, BX[kf_], a0_, 0, 0, 0, SCL_ONE, 0, SCL_ONE);       \
            a1_ = __builtin_amdgcn_mfma_scale_f32_32x32x64_f8f6f4(            \
                      e1_, BX[kf_], a1_, 0, 0, 0, SCL_ONE, 0, SCL_ONE);       \
        }                                                                     \
        _Pragma("unroll")                                                     \
        for (int q_ = 0; q_ < 4; ++q_) {                                      \
            const f32x4 ev0_ = *reinterpret_cast<const f32x4*>(e2 + (CC)*64 + q_*8 + h*4); \
            const f32x4 ev1_ = *reinterpret_cast<const f32x4*>(e2 + (CC)*64 + 32 + q_*8 + h*4); \
            _Pragma("unroll")                                                 \
            for (int r_ = 0; r_ < 4; ++r_) {                                  \
                best = fminf(best, fmaf(-INV2SCALE, a0_[4*q_+r_], ev0_[r_])); \
                best = fminf(best, fmaf(-INV2SCALE, a1_[4*q_+r_], ev1_[r_])); \
            }                                                                 \
        }                                                                     \
    } while (0)

// ---------------------------------------------------------------------------
// Kernel B (split path): distance + min only. B-fragments loaded DIRECTLY
// from xq (8 coalesced 16B loads/lane, no fp32 conversion phase) into 32
// pinned AGPRs; then R13's verified MX e-loop (16 chunks, dbuf gll16 staging,
// 1 barrier/chunk).  score = e2 - 2^-15 * (A.B)
// ---------------------------------------------------------------------------
__global__ __launch_bounds__(256)
void vq_dist(const char* __restrict__ xq, const char* __restrict__ embq,
             const float* __restrict__ e2, float* __restrict__ psc) {
    __shared__ char smem[32768];
    const int tid = threadIdx.x;
    const int wv = tid >> 6, ln = tid & 63;
    const int m = ln & 31, h = ln >> 5;
    const int sw = (m & 15) << 4;
    const int t = blockIdx.x * 4 + wv;     // wave's 32-row tile

    STAGE_EMB_Q(0, 0);

    i32x8 bx[4];
#pragma unroll
    for (int kf = 0; kf < 4; ++kf) {
        const char* p = xq + (((t * 4 + kf) * 2 + h) << 10) + m * 32;
        const i32x4 lo = *reinterpret_cast<const i32x4*>(p);
        const i32x4 hi = *reinterpret_cast<const i32x4*>(p + 16);
        i32x8 f;
#pragma unroll
        for (int d = 0; d < 4; ++d) { f[d] = lo[d]; f[d + 4] = hi[d]; }
        bx[kf] = f;
        asm volatile("" : "+a"(bx[kf]));   // pin to AGPR (R8/R13-verified)
    }

    __syncthreads();   // chunk 0 staged

    float best = 3.0e38f;
    for (int c = 0; c < 16; ++c) {
        if (c < 15) STAGE_EMB_Q(c + 1, (c + 1) & 1);
        TLOOP_MX(bx, c);
        __syncthreads();
    }

    best = fminf(best, __shfl_xor(best, 32));
    float contrib = (h == 0) ? best : 0.f;
#pragma unroll
    for (int o = 32; o; o >>= 1) contrib += __shfl_down(contrib, o);

    float* wsf = reinterpret_cast<float*>(smem);
    if (ln == 0) wsf[wv] = contrib;
    __syncthreads();
    if (tid == 0) psc[blockIdx.x] = (wsf[0] + wsf[1]) + (wsf[2] + wsf[3]);
}

// ---------------------------------------------------------------------------
// Fused fallback (R13 verbatim, 88.8us verified) — used if ws too small.
// ---------------------------------------------------------------------------
__global__ __launch_bounds__(256)
void vq_fused(const float* __restrict__ x, float* __restrict__ out,
              const char* __restrict__ embq, const float* __restrict__ e2,
              float* __restrict__ psc) {
    __shared__ char smem[32768];
    const int tid = threadIdx.x;
    const int wv = tid >> 6, ln = tid & 63;
    const int m = ln & 31, h = ln >> 5;
    const int sw = (m & 15) << 4;

    const int row_base = blockIdx.x << 7;
    const int b = row_base >> 12, n_base = row_base & 4095;
    const unsigned base0 = (unsigned)(b * (EMB_DIM * HW) + n_base + wv * 32 + m);

    STAGE_EMB_Q(0, 0);

    float x2s = 0.f;
    i32x8 bx[4];
#pragma unroll
    for (int kf = 0; kf < 4; ++kf) {
        const unsigned kb = base0 + (unsigned)((kf * 64 + h * 32) * HW);
        unsigned dw[8];
#pragma unroll
        for (int half = 0; half < 2; ++half) {
            float v[16];
#pragma unroll
            for (int j = 0; j < 16; ++j) {
                const unsigned o = kb + (unsigned)((half * 16 + j) * HW);
                const float f = x[o];
                out[o] = f;
                x2s += f * f;
                v[j] = f;
            }
#pragma unroll
            for (int d = 0; d < 4; ++d) {
                unsigned tw = 0;
                tw = (unsigned)__builtin_amdgcn_cvt_pk_fp8_f32(v[4*d],   v[4*d+1], (int)tw, false);
                tw = (unsigned)__builtin_amdgcn_cvt_pk_fp8_f32(v[4*d+2], v[4*d+3], (int)tw, true);
                dw[half * 4 + d] = tw;
            }
            __builtin_amdgcn_sched_barrier(0);
        }
        i32x8 f8;
#pragma unroll
        for (int d = 0; d < 8; ++d) f8[d] = (int)dw[d];
        bx[kf] = f8;
        asm volatile("" : "+a"(bx[kf]));
        __builtin_amdgcn_sched_barrier(0);
    }

    __syncthreads();

    float best = 3.0e38f;
    for (int c = 0; c < 16; ++c) {
        if (c < 15) STAGE_EMB_Q(c + 1, (c + 1) & 1);
        TLOOP_MX(bx, c);
        __syncthreads();
    }

    best = fminf(best, __shfl_xor(best, 32));
    float contrib = x2s + ((h == 0) ? best : 0.f);
#pragma unroll
    for (int o = 32; o; o >>= 1) contrib += __shfl_down(contrib, o);

    float* wsf = reinterpret_cast<float*>(smem);
    if (ln == 0) wsf[wv] = contrib;
    __syncthreads();
    if (tid == 0) psc[blockIdx.x] = (wsf[0] + wsf[1]) + (wsf[2] + wsf[3]);
}

// ---------------------------------------------------------------------------
// Finalize: deterministic tree-reduce; npx2 selects whether px2 contributes.
// ---------------------------------------------------------------------------
__global__ __launch_bounds__(256) void finalize(const float* __restrict__ psc,
                                                const float* __restrict__ px2,
                                                int use_px2,
                                                float* __restrict__ out_loss) {
    __shared__ float red[256];
    const int t = threadIdx.x;
    float s = 0.f;
#pragma unroll
    for (int i = 0; i < DIST_BLOCKS / 256; ++i) s += psc[t + i * 256];
    if (use_px2) {
#pragma unroll
        for (int i = 0; i < COPYQ_BLOCKS / 256; ++i) s += px2[t + i * 256];
    }
    red[t] = s;
    __syncthreads();
    for (int hh = 128; hh; hh >>= 1) {
        if (t < hh) red[t] += red[t + hh];
        __syncthreads();
    }
    if (t == 0) *out_loss = 1.25f * red[0] / (float)TOT_ELEMS;
}

extern "C" void kernel_launch(void* const* d_in, const int* in_sizes, int n_in,
                              void* d_out, int out_size, void* d_ws, size_t ws_size,
                              hipStream_t stream) {
    const float* x = (const float*)d_in[0];
    const float* emb = (const float*)d_in[1];
    float* out = (float*)d_out;
    char* ws = (char*)d_ws;

    char*  embq = ws + WS_EMBQ_OFF;
    float* e2   = (float*)(ws + WS_E2_OFF);
    float* psc  = (float*)(ws + WS_PSC_OFF);
    float* px2  = (float*)(ws + WS_PX2_OFF);
    char*  xq   = ws + WS_XQ_OFF;

    prep_emb<<<N_EMB, 64, 0, stream>>>(emb, embq, e2);
    if (ws_size >= (size_t)WS_NEED) {
        copy_quant<<<COPYQ_BLOCKS, 256, 0, stream>>>(x, out, xq, px2);
        vq_dist<<<DIST_BLOCKS, 256, 0, stream>>>(xq, embq, e2, psc);
        finalize<<<1, 256, 0, stream>>>(psc, px2, 1, out + TOT_ELEMS);
    } else {
        vq_fused<<<FUSED_BLOCKS, 256, 0, stream>>>(x, out, embq, e2, psc);
        finalize<<<1, 256, 0, stream>>>(psc, px2, 0, out + TOT_ELEMS);
    }
}